// Round 1
// baseline (360.303 us; speedup 1.0000x reference)
//
#include <hip/hip_runtime.h>

namespace {

constexpr float C2  = 0.2f;   // DT/DX^2 (stencil coefficient)
constexpr float DTC = 0.2f;   // DT
constexpr float IDT = 5.0f;   // 1/DT

// XOR-swizzled LDS layout: float4 unit q (0..15) of row (0..63) lives at
// float4-index row*16 + (q ^ (row&15)). Spreads b128 bank-starts across all
// 8 4-bank groups for wave-wide row reads.
__device__ __forceinline__ int ldsOff(int row, int q) {
    return ((row << 4) + (q ^ (row & 15))) << 2;   // float offset
}

// 256 blocks = 8 "parts" per batch, every block runs the full 4-field scan
// redundantly; block `part` stores only x-rows [8*part, 8*part+8).
//
// Round-2 changes:
//  * 1024-thread blocks (4 cells/thread instead of 8): same per-CU VALU/LDS
//    work, but 16 waves/CU instead of 8 (2 -> 4 waves/SIMD). Round-2 wall was
//    latency: occupancy 21.6%, VALUBusy 45% -- neither pipe saturated.
//  * XCD-aligned part mapping: blockIdx = part*32 + b, so all 8 parts of a
//    batch share blockIdx%8 (= XCD) and W is fetched once per XCD's L2
//    (round-2 FETCH_SIZE was 131 MB vs 33.5 MB ideal from 8-way cross-XCD
//    re-fetch).
__global__ __launch_bounds__(1024, 4)
void fused_scan(const float* __restrict__ W, float* __restrict__ out) {
    // double-buffered scan state: one barrier per iteration. 128 KB LDS pins
    // 1 block/CU so 256 blocks spread over all 256 CUs.
    __shared__ float sxi[2][4096];
    __shared__ float s4 [2][4096];
    __shared__ float s5 [2][4096];
    __shared__ float s6 [2][4096];

    const int tid  = threadIdx.x;
    // XCD-aligned mapping: parts of one batch differ by 32 in blockIdx ->
    // identical blockIdx%8 -> same XCD -> shared L2 image of W.
    const int b    = blockIdx.x & 31;
    const int part = blockIdx.x >> 5;

    const int x  = tid >> 4;       // row 0..63
    const int yc = tid & 15;       // y-chunk 0..15 (4 consecutive y each)
    const int yo = yc << 2;        // first y of this thread
    const int q0 = yc;             // float4 index within row

    const bool mine = ((tid >> 7) == part);   // wave-uniform store guard

    // wave = 4 consecutive rows x 16 y-chunks; y+-1 neighbors are in-wave
    const int lane   = tid & 63;
    const int laneYm = (lane & 48) | ((yc - 1) & 15);
    const int laneYp = (lane & 48) | ((yc + 1) & 15);

    const int xm = (x + 63) & 63;
    const int xp = (x + 1) & 63;
    // I2 source row: x-1 for x>0 (== xm), row 62 for x==0 (x==63's xm==62 too)

    const bool xedge = (x == 0) || (x == 63);
    const bool crnLo = xedge && (yc == 0);    // y==0 is a grid corner
    const bool crnHi = xedge && (yc == 15);   // y==63 is a grid corner

    float cxi[4], c4[4], c5[4], c6[4], xprev[4], wprev[4];
    #pragma unroll
    for (int j = 0; j < 4; ++j) {
        cxi[j] = 0.0f; c4[j] = 0.0f; c5[j] = 0.0f; c6[j] = 0.0f;
        xprev[j] = 0.0f; wprev[j] = 0.0f;
    }

    const float4 z4 = make_float4(0.0f, 0.0f, 0.0f, 0.0f);
    *(float4*)&sxi[0][ldsOff(x, q0)] = z4;
    *(float4*)&s4 [0][ldsOff(x, q0)] = z4;
    *(float4*)&s5 [0][ldsOff(x, q0)] = z4;
    *(float4*)&s6 [0][ldsOff(x, q0)] = z4;
    __syncthreads();

    const float* Wb = W   + (size_t)b * 64 * 4096;
    float*       oB = out + (size_t)b * 64 * 4096 * 7;

    // prefetch W slice for t=0
    float wt[4];
    *(float4*)&wt[0] = *(const float4*)(Wb + x * 64 + yo);

    int cb = 0;
    for (int t = 0; t < 64; ++t) {
        // ---- prefetch W for t+1 (overlaps with LDS + store work) ----
        float wnext[4];
        if (t < 63)
            *(float4*)&wnext[0] = *(const float4*)(Wb + (t + 1) * 4096 + x * 64 + yo);

        float dw[4];
        #pragma unroll
        for (int j = 0; j < 4; ++j)
            dw[j] = (t == 0) ? 0.0f : (wt[j] - wprev[j]) * IDT;
        #pragma unroll
        for (int j = 0; j < 4; ++j) wprev[j] = wt[j];

        // ---- xi-field x-neighbors (state t); xm row doubles as I2 source ----
        float nbm[4], nbp[4];
        *(float4*)&nbm[0] = *(const float4*)&sxi[cb][ldsOff(xm, q0)];
        *(float4*)&nbp[0] = *(const float4*)&sxi[cb][ldsOff(xp, q0)];

        float xi2[4];
        if (x == 0) {   // only wave 0's x==0 lanes take this masked extra read
            *(float4*)&xi2[0] = *(const float4*)&sxi[cb][ldsOff(62, q0)];
        } else {
            #pragma unroll
            for (int j = 0; j < 4; ++j) xi2[j] = nbm[j];
        }

        // ---- store the 7 channels at time t (only the owning waves) ----
        if (mine) {
            float4 ov[7];
            float* o = (float*)ov;
            #pragma unroll
            for (int j = 0; j < 4; ++j) {
                o[j * 7 + 0] = dw[j];
                o[j * 7 + 1] = cxi[j];
                o[j * 7 + 2] = (t == 0) ? 0.0f : -xprev[j];  // I1; t=0 fixed at t=63
                o[j * 7 + 3] = -xi2[j];                      // I2
                o[j * 7 + 4] = c4[j];
                o[j * 7 + 5] = c5[j];
                o[j * 7 + 6] = c6[j];
            }
            float4* dst = (float4*)(oB + ((size_t)t * 4096 + x * 64 + yo) * 7);
            #pragma unroll
            for (int k = 0; k < 7; ++k) dst[k] = ov[k];
        }

        if (t == 63) {
            // deferred: ch2 at t=0 is -I_xi[62] = -xprev (same thread overwrites)
            if (mine) {
                float* p0 = oB + (size_t)(x * 64 + yo) * 7 + 2;
                #pragma unroll
                for (int j = 0; j < 4; ++j) p0[j * 7] = -xprev[j];
            }
        } else {
            const int nb = cb ^ 1;

            // ---- forcings at time t ----
            float g4v[4], g5v[4], g6v[4];
            #pragma unroll
            for (int j = 0; j < 4; ++j) {
                g4v[j] = dw[j] * cxi[j];          // dW * I_xi
                g5v[j] = cxi[j] * cxi[j];         // I_xi^2
                g6v[j] = xprev[j] * xi2[j];       // (-I_xi[t-1]) * (-shift(I_xi[t]))
            }
            #pragma unroll
            for (int j = 0; j < 4; ++j) xprev[j] = cxi[j];

            // ---- one explicit-Euler step per field ----
            auto stepCore = [&](float* c, const float* nm, const float* np_,
                                const float* g) {
                const float ym = __shfl(c[3], laneYm, 64);   // u[x, yo-1] (periodic)
                const float yp = __shfl(c[0], laneYp, 64);   // u[x, yo+4] (periodic)
                float n[4];
                #pragma unroll
                for (int j = 0; j < 4; ++j) {
                    const float left  = (j == 0) ? ym : c[j - 1];
                    const float right = (j == 3) ? yp : c[j + 1];
                    float lap = nm[j] + np_[j] + left + right - 4.0f * c[j];
                    if ((j == 0 && crnLo) || (j == 3 && crnHi)) lap = 0.0f; // corners
                    n[j] = c[j] + C2 * lap + g[j] * DTC;
                }
                #pragma unroll
                for (int j = 0; j < 4; ++j) c[j] = n[j];
            };
            auto stepField = [&](const float* sArr, float* c, const float* g) {
                float nm[4], np_[4];
                *(float4*)&nm[0]  = *(const float4*)&sArr[ldsOff(xm, q0)];
                *(float4*)&np_[0] = *(const float4*)&sArr[ldsOff(xp, q0)];
                stepCore(c, nm, np_, g);
            };

            stepCore (cxi, nbm, nbp, dw);       // xi: neighbors already loaded
            stepField(&s4[cb][0], c4, g4v);
            stepField(&s5[cb][0], c5, g5v);
            stepField(&s6[cb][0], c6, g6v);

            // write state t+1 into the other buffer; single barrier
            *(float4*)&sxi[nb][ldsOff(x, q0)] = *(float4*)&cxi[0];
            *(float4*)&s4 [nb][ldsOff(x, q0)] = *(float4*)&c4 [0];
            *(float4*)&s5 [nb][ldsOff(x, q0)] = *(float4*)&c5 [0];
            *(float4*)&s6 [nb][ldsOff(x, q0)] = *(float4*)&c6 [0];
            __syncthreads();
            cb = nb;

            #pragma unroll
            for (int j = 0; j < 4; ++j) wt[j] = wnext[j];
        }
    }
}

} // namespace

extern "C" void kernel_launch(void* const* d_in, const int* in_sizes, int n_in,
                              void* d_out, int out_size, void* d_ws, size_t ws_size,
                              hipStream_t stream) {
    const float* W  = (const float*)d_in[0];
    float* out      = (float*)d_out;
    hipLaunchKernelGGL(fused_scan, dim3(256), dim3(1024), 0, stream, W, out);
}